// Round 6
// baseline (167.502 us; speedup 1.0000x reference)
//
#include <hip/hip_runtime.h>
#include <hip/hip_bf16.h>
#include <hip/hip_fp16.h>
#include <stdint.h>

typedef _Float16 half8 __attribute__((ext_vector_type(8)));
typedef _Float16 half4_t __attribute__((ext_vector_type(4)));
typedef float f32x4 __attribute__((ext_vector_type(4)));

// async global->LDS, 16B per lane. LDS dst must be wave-uniform base + lane*16.
__device__ __forceinline__ void lds_load16(const _Float16* g, _Float16* l) {
    __builtin_amdgcn_global_load_lds(
        (const __attribute__((address_space(1))) void*)g,
        (__attribute__((address_space(3))) void*)l, 16, 0, 0);
}

// ---------------------------------------------------------------------------
// fp32 -> fp16 conversions: nodes (8192x512), Wcat = [Wq;Wk;Wv], Wo
// ---------------------------------------------------------------------------
__global__ __launch_bounds__(256) void prep_convert(
    const float* __restrict__ nodes, const float* __restrict__ wq,
    const float* __restrict__ wk, const float* __restrict__ wv,
    const float* __restrict__ wo,
    _Float16* __restrict__ x16, _Float16* __restrict__ wcat,
    _Float16* __restrict__ wo16)
{
    const int t = blockIdx.x * 256 + threadIdx.x;   // 0 .. 1048575
    {
        const float4 v = ((const float4*)nodes)[t];
        half4_t o;
        o[0] = (_Float16)v.x; o[1] = (_Float16)v.y;
        o[2] = (_Float16)v.z; o[3] = (_Float16)v.w;
        *(half4_t*)(x16 + (size_t)t * 4) = o;
    }
    if (t < 65536) {
        float4 v; half4_t o;
        v = ((const float4*)wq)[t];
        o[0]=(_Float16)v.x; o[1]=(_Float16)v.y; o[2]=(_Float16)v.z; o[3]=(_Float16)v.w;
        *(half4_t*)(wcat + (size_t)t * 4) = o;
        v = ((const float4*)wk)[t];
        o[0]=(_Float16)v.x; o[1]=(_Float16)v.y; o[2]=(_Float16)v.z; o[3]=(_Float16)v.w;
        *(half4_t*)(wcat + 262144 + (size_t)t * 4) = o;
        v = ((const float4*)wv)[t];
        o[0]=(_Float16)v.x; o[1]=(_Float16)v.y; o[2]=(_Float16)v.z; o[3]=(_Float16)v.w;
        *(half4_t*)(wcat + 524288 + (size_t)t * 4) = o;
        v = ((const float4*)wo)[t];
        o[0]=(_Float16)v.x; o[1]=(_Float16)v.y; o[2]=(_Float16)v.z; o[3]=(_Float16)v.w;
        *(half4_t*)(wo16 + (size_t)t * 4) = o;
    }
}

// ---------------------------------------------------------------------------
// QKV projection: X[8192,512] @ Wcat[1536,512]^T -> scatter q/k/v [bh][i][d]
// q is pre-scaled by 1/sqrt(64) here (free in the epilogue).
// ---------------------------------------------------------------------------
__global__ __launch_bounds__(256, 3) void gemm_qkv(
    const _Float16* __restrict__ X, const _Float16* __restrict__ Wcat,
    const float* __restrict__ bq, const float* __restrict__ bk,
    const float* __restrict__ bv,
    _Float16* __restrict__ q16, _Float16* __restrict__ k16,
    _Float16* __restrict__ v16)
{
    __shared__ _Float16 As[128 * 32];
    __shared__ _Float16 Bs[128 * 32];
    const int t = threadIdx.x;
    const int bm = blockIdx.x, bn = blockIdx.y;
    const int wave = t >> 6, lane = t & 63;
    const int wm = (wave >> 1) * 64, wn = (wave & 1) * 64;
    const int quad = lane >> 4, l16 = lane & 15;

    f32x4 acc[4][4];
#pragma unroll
    for (int a = 0; a < 4; a++)
#pragma unroll
        for (int b2 = 0; b2 < 4; b2++) acc[a][b2] = (f32x4){0.f, 0.f, 0.f, 0.f};

    const _Float16* Ab = X + (size_t)bm * 128 * 512;
    const _Float16* Bb = Wcat + (size_t)bn * 128 * 512;
    const int srow = t >> 2, scol = (t & 3) * 8;

    for (int k0 = 0; k0 < 512; k0 += 32) {
        __syncthreads();
        lds_load16(Ab + (size_t)srow * 512 + k0 + scol, As + t * 8);
        lds_load16(Ab + (size_t)(srow + 64) * 512 + k0 + scol, As + 2048 + t * 8);
        lds_load16(Bb + (size_t)srow * 512 + k0 + scol, Bs + t * 8);
        lds_load16(Bb + (size_t)(srow + 64) * 512 + k0 + scol, Bs + 2048 + t * 8);
        __syncthreads();
        half8 af[4], bf[4];
#pragma unroll
        for (int mi = 0; mi < 4; mi++)
            af[mi] = *(const half8*)&As[(wm + mi * 16 + l16) * 32 + quad * 8];
#pragma unroll
        for (int ni = 0; ni < 4; ni++)
            bf[ni] = *(const half8*)&Bs[(wn + ni * 16 + l16) * 32 + quad * 8];
#pragma unroll
        for (int mi = 0; mi < 4; mi++)
#pragma unroll
            for (int ni = 0; ni < 4; ni++)
                acc[mi][ni] = __builtin_amdgcn_mfma_f32_16x16x32_f16(
                    af[mi], bf[ni], acc[mi][ni], 0, 0, 0);
    }

    const int sel = bn >> 2;
    const float* bias = sel == 0 ? bq : (sel == 1 ? bk : bv);
    _Float16* outp = sel == 0 ? q16 : (sel == 1 ? k16 : v16);
    const float scale = sel == 0 ? 0.125f : 1.0f;   // fold 1/sqrt(D) into q
    const int colbase = (bn & 3) * 128 + wn + l16;
#pragma unroll
    for (int mi = 0; mi < 4; mi++) {
#pragma unroll
        for (int r = 0; r < 4; r++) {
            const int m = bm * 128 + wm + mi * 16 + quad * 4 + r;
            const int ii = m >> 3, bb = m & 7;
#pragma unroll
            for (int ni = 0; ni < 4; ni++) {
                const int f = colbase + ni * 16;
                const int hh = f >> 6, dd = f & 63;
                const float val = (acc[mi][ni][r] + bias[f]) * scale;
                outp[(size_t)((bb * 8 + hh) * 1024 + ii) * 64 + dd] = (_Float16)val;
            }
        }
    }
}

// ---------------------------------------------------------------------------
// V transpose: v16 [bh][j][d] -> vT16 [bh][d][j]   (verified in R2)
// ---------------------------------------------------------------------------
__global__ __launch_bounds__(256) void transpose_v(
    const _Float16* __restrict__ v16, _Float16* __restrict__ vT16)
{
    __shared__ _Float16 T[64][72];
    const int bh = blockIdx.y, jt = blockIdx.x * 64;
    const int t = threadIdx.x;
    const int r = t >> 2, c = (t & 3) * 16;
    const _Float16* src = v16 + ((size_t)bh * 1024 + jt) * 64;
    *(half8*)&T[r][c]     = *(const half8*)(src + (size_t)r * 64 + c);
    *(half8*)&T[r][c + 8] = *(const half8*)(src + (size_t)r * 64 + c + 8);
    __syncthreads();
    _Float16* dst = vT16 + (size_t)bh * 64 * 1024 + jt;
    half8 o0, o1;
#pragma unroll
    for (int e = 0; e < 8; e++) { o0[e] = T[c + e][r]; o1[e] = T[c + 8 + e][r]; }
    *(half8*)(dst + (size_t)r * 1024 + c) = o0;
    *(half8*)(dst + (size_t)r * 1024 + c + 8) = o1;
}

// ---------------------------------------------------------------------------
// Flash-style MFMA attention, S computed TRANSPOSED to vectorize LDS traffic.
// Block = (b,h) x 128 q-rows; grid (64,8): x=bh -> XCD-local K/V reuse.
// S^T = K*Q^T (mfma with swapped operands): thread holds 4 consecutive j,
// fixed i -> P stored as ds_write_b64, edge bias loaded as float4.
// V pre-transposed globally -> b128 staging (no scalar LDS transpose).
// Q-fragments hoisted out of the j-loop (jt-invariant).
// Register prefetch of next tile's K/V/edges (no vmcnt drain at barriers).
// ---------------------------------------------------------------------------
__global__ __launch_bounds__(256, 2) void attn_fused(
    const _Float16* __restrict__ q16, const _Float16* __restrict__ k16,
    const _Float16* __restrict__ vT16, const float* __restrict__ edges,
    const float* __restrict__ rel_bias, _Float16* __restrict__ attn16)
{
    __shared__ _Float16 Qs[128][68];    // 17,408 B
    __shared__ _Float16 Ks[64][68];     //  8,704 B
    __shared__ _Float16 Vts[64][68];    //  8,704 B (V^T rows, b128 commit)
    __shared__ _Float16 Ps[128][72];    // 18,432 B (b64 stores 2-way max)
    __shared__ float    invs[128];      //     512 B

    const int t = threadIdx.x;
    const int bh = blockIdx.x;
    const int b = bh >> 3, h = bh & 7;
    const int i0 = blockIdx.y * 128;
    const int wave = t >> 6, lane = t & 63;
    const int quad = lane >> 4, l16 = lane & 15;
    const int qb = wave * 32;
    const float rb = rel_bias[h];
    const float SHIFT = 5.545177444f;   // 8*ln2 (cancels in O = sum pV / sum p)

    const _Float16* Qb = q16 + (size_t)bh * 1024 * 64;
    const _Float16* Kb = k16 + (size_t)bh * 1024 * 64;
    const _Float16* VbT = vT16 + (size_t)bh * 64 * 1024;

    const int srow = t >> 2, scol = (t & 3) * 16;

    {   // Q tile 128x64 (already scaled by 1/8 in gemm_qkv)
#pragma unroll
        for (int rr = 0; rr < 128; rr += 64) {
            *(half8*)&Qs[rr + srow][scol] =
                *(const half8*)(Qb + (size_t)(i0 + rr + srow) * 64 + scol);
            *(half8*)&Qs[rr + srow][scol + 8] =
                *(const half8*)(Qb + (size_t)(i0 + rr + srow) * 64 + scol + 8);
        }
    }

    f32x4 acc_o[2][4];
    float lsum[2] = {0.f, 0.f};
#pragma unroll
    for (int mt = 0; mt < 2; mt++)
#pragma unroll
        for (int nd = 0; nd < 4; nd++) acc_o[mt][nd] = (f32x4){0.f, 0.f, 0.f, 0.f};

    // ---- pipeline prologue: loads for jt=0 ----
    half8 kp0, kp1, vp0, vp1;
    f32x4 ebp[2][4];
    kp0 = *(const half8*)(Kb + (size_t)srow * 64 + scol);
    kp1 = *(const half8*)(Kb + (size_t)srow * 64 + scol + 8);
    vp0 = *(const half8*)(VbT + (size_t)srow * 1024 + scol);
    vp1 = *(const half8*)(VbT + (size_t)srow * 1024 + scol + 8);
#pragma unroll
    for (int mt = 0; mt < 2; mt++) {
        const size_t rowb = (size_t)(i0 + qb + mt * 16 + l16) * 1024;
#pragma unroll
        for (int jn = 0; jn < 4; jn++)
            ebp[mt][jn] = *(const f32x4*)(edges + rowb + jn * 16 + quad * 4);
    }

    __syncthreads();    // Qs staged

    // ---- hoist Q fragments (B-operand; jt-invariant) ----
    half8 qf[2][2];
#pragma unroll
    for (int mt = 0; mt < 2; mt++)
#pragma unroll
        for (int kk = 0; kk < 2; kk++)
            qf[mt][kk] = *(const half8*)&Qs[qb + mt * 16 + l16][kk * 32 + quad * 8];

    for (int jt = 0; jt < 1024; jt += 64) {
        __syncthreads();   // previous iteration's LDS reads done
        {   // commit prefetched K / V^T to LDS (all b128)
            *(half8*)&Ks[srow][scol]      = kp0;
            *(half8*)&Ks[srow][scol + 8]  = kp1;
            *(half8*)&Vts[srow][scol]     = vp0;
            *(half8*)&Vts[srow][scol + 8] = vp1;
        }
        f32x4 ebc[2][4];
#pragma unroll
        for (int mt = 0; mt < 2; mt++)
#pragma unroll
            for (int jn = 0; jn < 4; jn++) ebc[mt][jn] = ebp[mt][jn];
        __syncthreads();

        // ---- issue next-tile loads (consumed next iteration) ----
        const int jn2 = jt + 64;
        if (jn2 < 1024) {
            kp0 = *(const half8*)(Kb + (size_t)(jn2 + srow) * 64 + scol);
            kp1 = *(const half8*)(Kb + (size_t)(jn2 + srow) * 64 + scol + 8);
            vp0 = *(const half8*)(VbT + (size_t)srow * 1024 + jn2 + scol);
            vp1 = *(const half8*)(VbT + (size_t)srow * 1024 + jn2 + scol + 8);
#pragma unroll
            for (int mt = 0; mt < 2; mt++) {
                const size_t rowb = (size_t)(i0 + qb + mt * 16 + l16) * 1024;
#pragma unroll
                for (int jn = 0; jn < 4; jn++)
                    ebp[mt][jn] = *(const f32x4*)(edges + rowb + jn2 + jn * 16 + quad * 4);
            }
        }

        // ---- S^T = K Q^T : D[m=j][n=i] ----
        f32x4 s[2][4];
#pragma unroll
        for (int mt = 0; mt < 2; mt++)
#pragma unroll
            for (int jn = 0; jn < 4; jn++) s[mt][jn] = (f32x4){0.f, 0.f, 0.f, 0.f};
#pragma unroll
        for (int kk = 0; kk < 2; kk++) {
            half8 kf[4];
#pragma unroll
            for (int jn = 0; jn < 4; jn++)
                kf[jn] = *(const half8*)&Ks[jn * 16 + l16][kk * 32 + quad * 8];
#pragma unroll
            for (int mt = 0; mt < 2; mt++)
#pragma unroll
                for (int jn = 0; jn < 4; jn++)
                    s[mt][jn] = __builtin_amdgcn_mfma_f32_16x16x32_f16(
                        kf[jn], qf[mt][kk], s[mt][jn], 0, 0, 0);
        }

        // ---- bias + exp + rowsum + P->LDS as half4 (wave-private rows) ----
#pragma unroll
        for (int mt = 0; mt < 2; mt++)
#pragma unroll
            for (int jn = 0; jn < 4; jn++) {
                half4_t p4;
#pragma unroll
                for (int r = 0; r < 4; r++) {
                    const float sv = fmaf(ebc[mt][jn][r], rb, s[mt][jn][r]);
                    const float p = __expf(sv - SHIFT);
                    lsum[mt] += p;
                    p4[r] = (_Float16)p;
                }
                *(half4_t*)&Ps[qb + mt * 16 + l16][jn * 16 + quad * 4] = p4;
            }

        // ---- PV: O = P V  (A=P rows b128, B=V^T rows b128) ----
#pragma unroll
        for (int kk = 0; kk < 2; kk++) {
            half8 pa[2];
#pragma unroll
            for (int mt = 0; mt < 2; mt++)
                pa[mt] = *(const half8*)&Ps[qb + mt * 16 + l16][kk * 32 + quad * 8];
#pragma unroll
            for (int nd = 0; nd < 4; nd++) {
                half8 vb8 = *(const half8*)&Vts[nd * 16 + l16][kk * 32 + quad * 8];
#pragma unroll
                for (int mt = 0; mt < 2; mt++)
                    acc_o[mt][nd] = __builtin_amdgcn_mfma_f32_16x16x32_f16(
                        pa[mt], vb8, acc_o[mt][nd], 0, 0, 0);
            }
        }
    }

    // ---- finalize: reduce lsum across quads, distribute 1/l via LDS ----
#pragma unroll
    for (int mt = 0; mt < 2; mt++) {
        float l = lsum[mt];
        l += __shfl_xor(l, 16);
        l += __shfl_xor(l, 32);
        invs[qb + mt * 16 + l16] = 1.0f / l;   // all quads write same value
    }
    // wave-private rows -> no barrier needed
#pragma unroll
    for (int mt = 0; mt < 2; mt++)
#pragma unroll
        for (int r = 0; r < 4; r++) {
            const int i = i0 + qb + mt * 16 + quad * 4 + r;
            const float inv = invs[qb + mt * 16 + quad * 4 + r];
            _Float16* orow = attn16 + ((size_t)i * 8 + b) * 512 + h * 64;
#pragma unroll
            for (int nd = 0; nd < 4; nd++)
                orow[nd * 16 + l16] = (_Float16)(acc_o[mt][nd][r] * inv);
        }
}

// ---------------------------------------------------------------------------
// Output projection: attn16[8192,512] @ Wo[512,512]^T + bo -> d_out fp32
// 64x128 tiles -> grid (128,4) = 512 blocks = 2 blocks/CU.
// ---------------------------------------------------------------------------
__global__ __launch_bounds__(256, 4) void gemm_out(
    const _Float16* __restrict__ A, const _Float16* __restrict__ W,
    const float* __restrict__ bo, float* __restrict__ dout)
{
    __shared__ _Float16 As[64 * 32];
    __shared__ _Float16 Bs[128 * 32];
    const int t = threadIdx.x;
    const int bm = blockIdx.x, bn = blockIdx.y;
    const int wave = t >> 6, lane = t & 63;
    const int wm = (wave >> 1) * 32, wn = (wave & 1) * 64;
    const int quad = lane >> 4, l16 = lane & 15;

    f32x4 acc[2][4];
#pragma unroll
    for (int a = 0; a < 2; a++)
#pragma unroll
        for (int b2 = 0; b2 < 4; b2++) acc[a][b2] = (f32x4){0.f, 0.f, 0.f, 0.f};

    const _Float16* Ab = A + (size_t)bm * 64 * 512;
    const _Float16* Bb = W + (size_t)bn * 128 * 512;
    const int srow = t >> 2, scol = (t & 3) * 8;

    for (int k0 = 0; k0 < 512; k0 += 32) {
        __syncthreads();
        lds_load16(Ab + (size_t)srow * 512 + k0 + scol, As + t * 8);
        lds_load16(Bb + (size_t)srow * 512 + k0 + scol, Bs + t * 8);
        lds_load16(Bb + (size_t)(srow + 64) * 512 + k0 + scol, Bs + 2048 + t * 8);
        __syncthreads();
        half8 af[2], bf[4];
#pragma unroll
        for (int mi = 0; mi < 2; mi++)
            af[mi] = *(const half8*)&As[(wm + mi * 16 + l16) * 32 + quad * 8];
#pragma unroll
        for (int ni = 0; ni < 4; ni++)
            bf[ni] = *(const half8*)&Bs[(wn + ni * 16 + l16) * 32 + quad * 8];
#pragma unroll
        for (int mi = 0; mi < 2; mi++)
#pragma unroll
            for (int ni = 0; ni < 4; ni++)
                acc[mi][ni] = __builtin_amdgcn_mfma_f32_16x16x32_f16(
                    af[mi], bf[ni], acc[mi][ni], 0, 0, 0);
    }
#pragma unroll
    for (int mi = 0; mi < 2; mi++) {
#pragma unroll
        for (int r = 0; r < 4; r++) {
            const int m = bm * 64 + wm + mi * 16 + quad * 4 + r;
#pragma unroll
            for (int ni = 0; ni < 4; ni++) {
                const int n = bn * 128 + wn + ni * 16 + l16;
                dout[(size_t)m * 512 + n] = acc[mi][ni][r] + bo[n];
            }
        }
    }
}

// ---------------------------------------------------------------------------
extern "C" void kernel_launch(void* const* d_in, const int* in_sizes, int n_in,
                              void* d_out, int out_size, void* d_ws, size_t ws_size,
                              hipStream_t stream)
{
    (void)in_sizes; (void)n_in; (void)out_size; (void)ws_size;
    const float* nodes    = (const float*)d_in[0];
    const float* edges    = (const float*)d_in[1];
    const float* Wq       = (const float*)d_in[2];
    const float* bq       = (const float*)d_in[3];
    const float* Wk       = (const float*)d_in[4];
    const float* bk       = (const float*)d_in[5];
    const float* Wv       = (const float*)d_in[6];
    const float* bv       = (const float*)d_in[7];
    const float* rel_bias = (const float*)d_in[8];
    const float* Wo       = (const float*)d_in[9];
    const float* bo       = (const float*)d_in[10];
    float* out = (float*)d_out;

    char* ws = (char*)d_ws;
    _Float16* x16    = (_Float16*)(ws);              //  8,388,608 B
    _Float16* wcat   = (_Float16*)(ws +  8388608);   //  1,572,864 B
    _Float16* wo16   = (_Float16*)(ws +  9961472);   //    524,288 B
    _Float16* q16    = (_Float16*)(ws + 10485760);   //  8,388,608 B
    _Float16* k16    = (_Float16*)(ws + 18874368);   //  8,388,608 B
    _Float16* v16    = (_Float16*)(ws + 27262976);   //  8,388,608 B
    _Float16* attn16 = (_Float16*)(ws + 35651584);   //  8,388,608 B
    _Float16* vT16   = (_Float16*)(ws);              // reuses x16 (dead after gemm_qkv)

    hipLaunchKernelGGL(prep_convert, dim3(4096), dim3(256), 0, stream,
                       nodes, Wq, Wk, Wv, Wo, x16, wcat, wo16);
    hipLaunchKernelGGL(gemm_qkv, dim3(64, 12), dim3(256), 0, stream,
                       x16, wcat, bq, bk, bv, q16, k16, v16);
    hipLaunchKernelGGL(transpose_v, dim3(16, 64), dim3(256), 0, stream,
                       v16, vT16);
    hipLaunchKernelGGL(attn_fused, dim3(64, 8), dim3(256), 0, stream,
                       q16, k16, vT16, edges, rel_bias, attn16);
    hipLaunchKernelGGL(gemm_out, dim3(128, 4), dim3(256), 0, stream,
                       attn16, wo16, bo, out);
}